// Round 1
// 840.189 us; speedup vs baseline: 1.5128x; 1.5128x over previous
//
#include <hip/hip_runtime.h>

// ---------------------------------------------------------------------------
// Two-kernel fused zero-state-LSTM + softmax for MI355X (gfx950).
//
// K1 (prep): permute/pad/bf16-convert x -> A in XOR-swizzled granule layout
//            (+ W_ih gate rows i,g,o as B tiles, same layout). Coalesced
//            global reads via LDS slab; writes are the exact image that
//            global_load_lds will DMA linearly in K2.
// K2 (gemm): MT=64 rows x N=576 (3 gates x 192, padded), K=192 (padded),
//            6 k-slices of 32. 512 thr = 8 waves = 2 rowgroups x 4 colgroups;
//            wave = 32 rows x 144 cols (18 accs). Staging = pure 16B
//            global_load_lds; frag ds_read_b128 conflict-free via swizzle.
//            Cross-wave softmax combine through 2KB LDS.
// ---------------------------------------------------------------------------

typedef __attribute__((ext_vector_type(8))) short short8;   // 8 bf16
typedef __attribute__((ext_vector_type(4))) float float4v;  // MFMA acc

#define SEQ   240
#define HID   180
#define NROWS (2048 * SEQ)            // 491520
#define NBLK2 (NROWS / 64)            // 7680 gemm blocks (64 rows each)
#define WS_A_SHORTS   94371840ull     // 7680 tiles * 12288 shorts (64*192 bf16)
#define WS_TOTAL_BYTES 188964864ull   // A (188,743,680 B) + B (221,184 B)

__device__ __forceinline__ unsigned short f2bf(float f) {
    unsigned int u = __float_as_uint(f);
    u += 0x7fffu + ((u >> 16) & 1u);   // round-to-nearest-even
    return (unsigned short)(u >> 16);
}
__device__ __forceinline__ float fast_sig(float x) {
    return __builtin_amdgcn_rcpf(1.0f + __expf(-x));
}
__device__ __forceinline__ float fast_tanh(float x) {
    return 1.0f - 2.0f * __builtin_amdgcn_rcpf(__expf(2.0f * x) + 1.0f);
}
__device__ __forceinline__ void gload16(const void* g, void* l) {
    __builtin_amdgcn_global_load_lds((const __attribute__((address_space(1))) void*)g,
                                     (__attribute__((address_space(3))) void*)l, 16, 0, 0);
}

// ---------------------------------------------------------------------------
// Kernel 1: prep.  A-part: 2048 batches x 8 u-octants = 16384 blocks.
//   Block (b,uq): x in-rows [30*uq, 30*uq+30) of batch b -> 30 output rows
//   {b*240 + c*80 + uq*10 + ul : c in 0..2, ul in 0..9}, all 24 k-granules.
//   Granule (row,kk,qL) stored at tile*12288 + kk*2048 + (rloc*4 + qS)*8
//   shorts, qS = qL ^ ((rloc>>1)&3)  -> swizzled so K2's linear
//   global_load_lds + swizzled ds_read_b128 is bank-conflict-free.
// B-part: 54 blocks convert W_ih rows (gates i,g,o) into the same layout.
// ---------------------------------------------------------------------------
__global__ __launch_bounds__(256) void prep_kernel(
        const float* __restrict__ x, const float* __restrict__ Wih,
        unsigned short* __restrict__ ws) {
    __shared__ float slab[5400];           // 30 x-rows of 180 f32 = 21.6 KB
    const int bid = blockIdx.x, t = threadIdx.x;
    if (bid < 16384) {
        const int b = bid >> 3, uq = bid & 7;
        const float* xb = x + (size_t)b * 43200 + uq * 5400;
        for (int i = t; i < 1350; i += 256)
            ((float4*)slab)[i] = ((const float4*)xb)[i];      // coalesced
        __syncthreads();
        for (int i = t; i < 720; i += 256) {                  // 30 rows * 24 granules
            const int rr = i / 24, kq = i - rr * 24;
            const int kk = kq >> 2, qL = kq & 3;
            const int c = rr / 10, ul = rr - c * 10;
            const int row = b * 240 + c * 80 + uq * 10 + ul;
            const int k0 = kq * 8;
            short8 sv;
#pragma unroll
            for (int j = 0; j < 8; ++j) {
                const int k = k0 + j;
                float f = 0.0f;
                if (k < HID) {
                    const int tt = k / 60, w = k - tt * 60;
                    f = slab[(3 * ul + tt) * 180 + w * 3 + c];  // permute from LDS
                }
                sv[j] = (short)f2bf(f);
            }
            const int tile = row >> 6, rloc = row & 63;
            const int qS = qL ^ ((rloc >> 1) & 3);
            *(short8*)(ws + (size_t)tile * 12288 + kk * 2048 + (rloc * 4 + qS) * 8) = sv;
        }
    } else {
        const int i0 = (bid - 16384) * 256 + t;               // 0..13823 exactly
        const int n = i0 / 24, kq = i0 - n * 24;
        const int kk = kq >> 2, qL = kq & 3;
        const int chunk = n / 192, off = n - chunk * 192;
        const int k0 = kq * 8;
        short8 sv;
        if (off < HID) {
            const int g = (chunk == 0 ? 0 : (chunk == 1 ? 360 : 540)) + off;
            const float* wr = Wih + (size_t)g * HID;
#pragma unroll
            for (int j = 0; j < 8; ++j) {
                const int k = k0 + j;
                sv[j] = (short)((k < HID) ? f2bf(wr[k]) : 0);
            }
        } else {
#pragma unroll
            for (int j = 0; j < 8; ++j) sv[j] = 0;
        }
        const int qS = qL ^ ((n >> 1) & 3);
        *(short8*)(ws + WS_A_SHORTS + (size_t)kk * 18432 + (n * 4 + qS) * 8) = sv;
    }
}

// ---------------------------------------------------------------------------
// Kernel 2: GEMM + nonlinearity + softmax.
// ---------------------------------------------------------------------------
__global__ __launch_bounds__(512, 4) void gemm_kernel(
        const unsigned short* __restrict__ ws,
        const float* __restrict__ b_ih, const float* __restrict__ b_hh,
        float* __restrict__ out) {
    __shared__ short A_sl[2048];        //  64 rows x 32 bf16 ( 4,096 B)
    __shared__ short B_sl[18432];       // 576 rows x 32 bf16 (36,864 B)
    __shared__ float biasS[576];        //  2,304 B
    __shared__ float smxM[2][32][4];    //  1,024 B  [rg][row][cg] partial max
    __shared__ float smxS[2][32][4];    //  1,024 B  partial sum   (45.3 KB total)

    const int t = threadIdx.x;
    const int bk = blockIdx.x;
    const int lane = t & 63, wid = t >> 6;
    const int rg = wid >> 2, cg = wid & 3;   // rowgroup 0..1, colgroup 0..3
    const int ln = lane & 15, q = lane >> 4;

    for (int i = t; i < 576; i += 512) {
        const int chunk = i / 192, off = i - chunk * 192;
        float bv = 0.0f;
        if (off < HID) {
            const int g = (chunk == 0 ? 0 : (chunk == 1 ? 360 : 540)) + off;
            bv = b_ih[g] + b_hh[g];
        }
        biasS[i] = bv;
    }

    const unsigned short* Aws = ws + (size_t)bk * 12288;
    const unsigned short* Bws = ws + WS_A_SHORTS;

    // frag LDS offsets (shorts); swizzle matches prep layout -> conflict-free
    int aoff[2];
#pragma unroll
    for (int mt = 0; mt < 2; ++mt) {
        const int r = rg * 32 + mt * 16 + ln;
        aoff[mt] = (r * 4 + (q ^ ((r >> 1) & 3))) * 8;
    }
    int boff[9];
#pragma unroll
    for (int G = 0; G < 3; ++G)
#pragma unroll
        for (int sub = 0; sub < 3; ++sub) {
            const int n = G * 192 + cg * 48 + sub * 16 + ln;
            boff[G * 3 + sub] = (n * 4 + (q ^ ((n >> 1) & 3))) * 8;
        }

    float4v acc[2][9];
#pragma unroll
    for (int mt = 0; mt < 2; ++mt)
#pragma unroll
        for (int nt = 0; nt < 9; ++nt) acc[mt][nt] = (float4v){0.f, 0.f, 0.f, 0.f};

    for (int kk = 0; kk < 6; ++kk) {
        __syncthreads();                       // prev-slice frag reads done
        if (t < 256)                           // A slice: 256 granules of 16 B
            gload16(Aws + (size_t)kk * 2048 + t * 8, &A_sl[t * 8]);
#pragma unroll
        for (int r2 = 0; r2 < 4; ++r2) {       // B slice: 2304 granules
            const int i = t + r2 * 512;
            gload16(Bws + (size_t)kk * 18432 + i * 8, &B_sl[i * 8]);
        }
        if (t < 256) {
            const int i = t + 2048;
            gload16(Bws + (size_t)kk * 18432 + i * 8, &B_sl[i * 8]);
        }
        __syncthreads();                       // compiler drains vmcnt here

        const short8 af0 = *(const short8*)(&A_sl[aoff[0]]);
        const short8 af1 = *(const short8*)(&A_sl[aoff[1]]);
#pragma unroll
        for (int nt = 0; nt < 9; ++nt) {
            const short8 bf = *(const short8*)(&B_sl[boff[nt]]);
            acc[0][nt] = __builtin_amdgcn_mfma_f32_16x16x32_bf16(af0, bf, acc[0][nt], 0, 0, 0);
            acc[1][nt] = __builtin_amdgcn_mfma_f32_16x16x32_bf16(af1, bf, acc[1][nt], 0, 0, 0);
        }
    }

    // ---- epilogue: C[m = q*4+reg][n = 16*tile + ln]; cross-wave softmax ----
    float hv_[2][4][3];
#pragma unroll
    for (int mt = 0; mt < 2; ++mt) {
#pragma unroll
        for (int reg = 0; reg < 4; ++reg) {
            float m = -3.0e38f;
#pragma unroll
            for (int sub = 0; sub < 3; ++sub) {
                const int h = cg * 48 + sub * 16 + ln;
                const float gi = acc[mt][sub][reg]     + biasS[h];
                const float gg = acc[mt][3 + sub][reg] + biasS[192 + h];
                const float go = acc[mt][6 + sub][reg] + biasS[384 + h];
                const float cell = fast_sig(gi) * fast_tanh(gg);
                float hv = fast_sig(go) * fast_tanh(cell);
                hv = (h < HID) ? hv : -3.0e38f;
                hv_[mt][reg][sub] = hv;
                m = fmaxf(m, hv);
            }
#pragma unroll
            for (int s2 = 1; s2 < 16; s2 <<= 1) m = fmaxf(m, __shfl_xor(m, s2, 16));
            if (ln == 0) smxM[rg][mt * 16 + q * 4 + reg][cg] = m;
        }
    }
    __syncthreads();
#pragma unroll
    for (int mt = 0; mt < 2; ++mt) {
#pragma unroll
        for (int reg = 0; reg < 4; ++reg) {
            const float4 mv = *(const float4*)&smxM[rg][mt * 16 + q * 4 + reg][0];
            const float gm = fmaxf(fmaxf(mv.x, mv.y), fmaxf(mv.z, mv.w));
            float s = 0.0f;
#pragma unroll
            for (int sub = 0; sub < 3; ++sub) {
                const int h = cg * 48 + sub * 16 + ln;
                const float e = (h < HID) ? __expf(hv_[mt][reg][sub] - gm) : 0.0f;
                hv_[mt][reg][sub] = e;
                s += e;
            }
#pragma unroll
            for (int s2 = 1; s2 < 16; s2 <<= 1) s += __shfl_xor(s, s2, 16);
            if (ln == 0) smxS[rg][mt * 16 + q * 4 + reg][cg] = s;
        }
    }
    __syncthreads();
#pragma unroll
    for (int mt = 0; mt < 2; ++mt) {
#pragma unroll
        for (int reg = 0; reg < 4; ++reg) {
            const float4 sv4 = *(const float4*)&smxS[rg][mt * 16 + q * 4 + reg][0];
            const float inv = __builtin_amdgcn_rcpf(sv4.x + sv4.y + sv4.z + sv4.w);
            const int row = bk * 64 + rg * 32 + mt * 16 + q * 4 + reg;
            float* __restrict__ orow = out + (size_t)row * HID;
#pragma unroll
            for (int sub = 0; sub < 3; ++sub) {
                const int h = cg * 48 + sub * 16 + ln;
                if (h < HID) orow[h] = hv_[mt][reg][sub] * inv;
            }
        }
    }
}

// ---------------------------------------------------------------------------
// Fallback (previous best single-kernel) in case ws_size < 189 MB.
// ---------------------------------------------------------------------------
#define MT    128
#define NBLK  (NROWS / MT)
#define NP    576
#define LSTR  40

__global__ __launch_bounds__(512) void lstm_softmax_fallback(
        const float* __restrict__ x, const float* __restrict__ Wih,
        const float* __restrict__ b_ih, const float* __restrict__ b_hh,
        float* __restrict__ out) {
    __shared__ short A_sl[MT * LSTR];
    __shared__ short B_sl[NP * LSTR];
    __shared__ float biasS[NP];

    const int t = threadIdx.x;
    const int raw = blockIdx.x;
    const int vb  = (raw & 7) * (NBLK / 8) + (raw >> 3);
    const int r0  = vb * MT;

    for (int i = t; i < NP; i += 512) {
        const int chunk = i / 192, off = i - chunk * 192;
        float bv = 0.0f;
        if (off < HID) {
            const int g = (chunk == 0 ? 0 : (chunk == 1 ? 360 : 540)) + off;
            bv = b_ih[g] + b_hh[g];
        }
        biasS[i] = bv;
    }

    const int row_l = t >> 2;
    const int seg   = t & 3;
    const int grow  = r0 + row_l;
    const int bb    = grow / SEQ;
    const int sp    = grow - bb * SEQ;
    const int cc    = sp / 80;
    const int sb    = 3 * (sp - cc * 80);
    const float* xrow = x + (size_t)bb * (SEQ * HID) + cc;

    float4v acc[36];
#pragma unroll
    for (int j = 0; j < 36; ++j) acc[j] = (float4v){0.f, 0.f, 0.f, 0.f};

    const int lane = t & 63;
    const int wid  = t >> 6;
    const int ln   = lane & 15;
    const int q    = lane >> 4;

    for (int kk = 0; kk < 6; ++kk) {
        __syncthreads();
        {
            const int k0 = kk * 32 + seg * 8;
            short8 sv;
#pragma unroll
            for (int j = 0; j < 8; ++j) {
                const int k = k0 + j;
                float f = 0.0f;
                if (k < HID) {
                    const int tt = k / 60;
                    const int w  = k - tt * 60;
                    f = xrow[(sb + tt) * HID + w * 3];
                }
                sv[j] = (short)f2bf(f);
            }
            *(short8*)(&A_sl[row_l * LSTR + seg * 8]) = sv;
        }
        for (int i = t; i < NP * 4; i += 512) {
            const int n  = i >> 2;
            const int sg = i & 3;
            const int k0 = kk * 32 + sg * 8;
            const int chunk = n / 192, off = n - chunk * 192;
            short8 sv;
            if (off < HID) {
                const int g = (chunk == 0 ? 0 : (chunk == 1 ? 360 : 540)) + off;
                const float* wr = Wih + (size_t)g * HID;
#pragma unroll
                for (int j = 0; j < 8; ++j) {
                    float f = 0.0f;
                    const int k = k0 + j;
                    if (k < HID) f = wr[k];
                    sv[j] = (short)f2bf(f);
                }
            } else {
#pragma unroll
                for (int j = 0; j < 8; ++j) sv[j] = 0;
            }
            *(short8*)(&B_sl[n * LSTR + sg * 8]) = sv;
        }
        __syncthreads();

        const short8 a = *(const short8*)(&A_sl[(wid * 16 + ln) * LSTR + q * 8]);
#pragma unroll
        for (int j = 0; j < 36; ++j) {
            const short8 bf = *(const short8*)(&B_sl[(j * 16 + ln) * LSTR + q * 8]);
            acc[j] = __builtin_amdgcn_mfma_f32_16x16x32_bf16(a, bf, acc[j], 0, 0, 0);
        }
    }

    const int out_row_base = r0 + wid * 16 + q * 4;
#pragma unroll
    for (int reg = 0; reg < 4; ++reg) {
        const int row = out_row_base + reg;
        float ev[12];
        float hmax = -3.0e38f;
#pragma unroll
        for (int j = 0; j < 12; ++j) {
            const int h = j * 16 + ln;
            const float gi = acc[j][reg]      + biasS[h];
            const float gg = acc[j + 12][reg] + biasS[192 + h];
            const float go = acc[j + 24][reg] + biasS[384 + h];
            const float cell = fast_sig(gi) * fast_tanh(gg);
            float hv = fast_sig(go) * fast_tanh(cell);
            hv = (h < HID) ? hv : -3.0e38f;
            ev[j] = hv;
            hmax = fmaxf(hmax, hv);
        }
#pragma unroll
        for (int m = 1; m < 16; m <<= 1) hmax = fmaxf(hmax, __shfl_xor(hmax, m, 16));
        float ssum = 0.0f;
#pragma unroll
        for (int j = 0; j < 12; ++j) {
            const int h = j * 16 + ln;
            const float e = (h < HID) ? __expf(ev[j] - hmax) : 0.0f;
            ev[j] = e;
            ssum += e;
        }
#pragma unroll
        for (int m = 1; m < 16; m <<= 1) ssum += __shfl_xor(ssum, m, 16);
        const float inv = __builtin_amdgcn_rcpf(ssum);
        float* __restrict__ orow = out + (size_t)row * HID;
#pragma unroll
        for (int j = 0; j < 12; ++j) {
            const int h = j * 16 + ln;
            if (h < HID) orow[h] = ev[j] * inv;
        }
    }
}

extern "C" void kernel_launch(void* const* d_in, const int* in_sizes, int n_in,
                              void* d_out, int out_size, void* d_ws, size_t ws_size,
                              hipStream_t stream) {
    const float* x    = (const float*)d_in[0];
    const float* Wih  = (const float*)d_in[1];
    // d_in[2] = W_hh: dead (h0 == 0)
    const float* b_ih = (const float*)d_in[3];
    const float* b_hh = (const float*)d_in[4];
    float* out = (float*)d_out;
    if (d_ws && ws_size >= WS_TOTAL_BYTES) {
        unsigned short* ws = (unsigned short*)d_ws;
        hipLaunchKernelGGL(prep_kernel, dim3(16384 + 54), dim3(256), 0, stream, x, Wih, ws);
        hipLaunchKernelGGL(gemm_kernel, dim3(NBLK2), dim3(512), 0, stream, ws, b_ih, b_hh, out);
    } else {
        hipLaunchKernelGGL(lstm_softmax_fallback, dim3(NBLK), dim3(512), 0, stream,
                           x, Wih, b_ih, b_hh, out);
    }
}